// Round 9
// baseline (51.553 us; speedup 1.0000x reference)
//
#include <hip/hip_runtime.h>
#include <hip/hip_bf16.h>

// MoE layer, MI355X gfx950. B=16, C=64, H=W=128, E=8, TOPK=2.
// out = x + sum_{s in top2} w_s * (W2_e @ gelu((W1_e @ x + b1_e) * k) + b2_e)
// 3-kernel structure: pool+wconv, gate, fused MFMA main.
// moe_main: 4096 blocks (1 batch x 64-px tile each), 2 barriers/block,
// 3 LDS buffers (24 KB), residual kept in registers (f32 exact).

#define BB 16
#define CC 64
#define EE 8
#define HWPX 16384

typedef __bf16 bf16x8 __attribute__((ext_vector_type(8)));
typedef float f32x4 __attribute__((ext_vector_type(4)));

__device__ __forceinline__ unsigned packbf2(float lo, float hi) {
    // compiler emits v_cvt_pk_bf16_f32 (RNE)
    __bf16 a = (__bf16)lo, b = (__bf16)hi;
    unsigned short ua = __builtin_bit_cast(unsigned short, a);
    unsigned short ub = __builtin_bit_cast(unsigned short, b);
    return ((unsigned)ub << 16) | (unsigned)ua;
}

// XOR-swizzled dword index into a [64 px][32 dword] LDS tile.
// Same involution on write and read; 16B chunks XORed by (px&7).
__device__ __forceinline__ int swz(int px, int d) {
    return px * 32 + ((d & ~3) ^ ((px & 7) << 2)) + (d & 3);
}

// ---------------- kernel 1: global avg pool (blocks 0..1023) + W-conv (blocks 1024..1151) ----------------
__global__ __launch_bounds__(256) void pool_conv_kernel(
    const float* __restrict__ x, float* __restrict__ pooled,
    const float* __restrict__ W1, const float* __restrict__ W2,
    __bf16* __restrict__ W1b, __bf16* __restrict__ W2b) {
    int blk = blockIdx.x;
    if (blk < BB * CC) {
        const float4* p = (const float4*)(x + (size_t)blk * HWPX);
        float s = 0.f;
        for (int i = threadIdx.x; i < HWPX / 4; i += 256) {
            float4 v = p[i];
            s += (v.x + v.y) + (v.z + v.w);
        }
        #pragma unroll
        for (int off = 32; off > 0; off >>= 1) s += __shfl_down(s, off);
        __shared__ float ls[4];
        if ((threadIdx.x & 63) == 0) ls[threadIdx.x >> 6] = s;
        __syncthreads();
        if (threadIdx.x == 0) pooled[blk] = ((ls[0] + ls[1]) + (ls[2] + ls[3])) * (1.0f / (float)HWPX);
    } else {
        int i = (blk - BB * CC) * 256 + threadIdx.x;  // 0..32767
        W1b[i] = (__bf16)W1[i];
        W2b[i] = (__bf16)W2[i];
    }
}

// ---------------- kernel 2: gate logits + softmax + top2 ----------------
__global__ void gate_kernel(const float* __restrict__ pooled,
                            const float* __restrict__ Wg,
                            const float* __restrict__ bg,
                            int* __restrict__ gidx, float* __restrict__ gw) {
    int b = threadIdx.x;
    if (b >= BB) return;
    float logits[EE];
    #pragma unroll
    for (int e = 0; e < EE; ++e) logits[e] = bg[e];
    for (int c = 0; c < CC; ++c) {
        float pv = pooled[b * CC + c];
        #pragma unroll
        for (int e = 0; e < EE; ++e) logits[e] = fmaf(pv, Wg[c * EE + e], logits[e]);
    }
    float m = logits[0];
    #pragma unroll
    for (int e = 1; e < EE; ++e) m = fmaxf(m, logits[e]);
    float w[EE]; float den = 0.f;
    #pragma unroll
    for (int e = 0; e < EE; ++e) { w[e] = expf(logits[e] - m); den += w[e]; }
    float inv = 1.0f / den;
    #pragma unroll
    for (int e = 0; e < EE; ++e) w[e] *= inv;
    int i0 = 0;
    #pragma unroll
    for (int e = 1; e < EE; ++e) if (w[e] > w[i0]) i0 = e;
    int i1 = -1;
    #pragma unroll
    for (int e = 0; e < EE; ++e) {
        if (e == i0) continue;
        if (i1 < 0 || w[e] > w[i1]) i1 = e;
    }
    gidx[b * 2 + 0] = i0; gidx[b * 2 + 1] = i1;
    gw[b * 2 + 0] = w[i0]; gw[b * 2 + 1] = w[i1];
}

// ---------------- kernel 3: fused top-2 expert MLP + residual (MFMA) ----------------
// Grid: 4096 = 16 batches x 256 tiles (64 px). Block: 256 thr = 4 waves.
// Thread (w,g,l15) owns channels 16w+4g..+3 x pixels {16cb+l15}: loads them
// once (f32 residual regs), stages bf16 to LDS, stores the final output.
// 2 barriers total; 3 x 8KB swizzled LDS buffers (xT, hT0, hT1) -> 6 blocks/CU.
__global__ __launch_bounds__(256) void moe_main(
    const float* __restrict__ x, const float* __restrict__ kvec,
    const __bf16* __restrict__ W1b, const float* __restrict__ b1,
    const __bf16* __restrict__ W2b, const float* __restrict__ b2,
    const int* __restrict__ gidx, const float* __restrict__ gw,
    float* __restrict__ out) {

    __shared__ unsigned int LX[64 * 32];
    __shared__ unsigned int LH0[64 * 32];
    __shared__ unsigned int LH1[64 * 32];

    const int blk = blockIdx.x;
    const int b = blk >> 8;            // batch
    const int P0 = (blk & 255) << 6;   // tile base pixel
    const int t = threadIdx.x;
    const int w = t >> 6;              // wave id
    const int l = t & 63;
    const int g = l >> 4;              // 16-lane group
    const int l15 = l & 15;

    const int arow = 16 * w + l15;     // A-fragment row (out channel)
    const int r0w = 16 * w + 4 * g;    // this lane's first owned channel
    const int d0 = 8 * w + 2 * g;      // LDS dword col of channels r0w..r0w+3

    // ---- gate results ----
    const int e0 = __builtin_amdgcn_readfirstlane(gidx[b * 2 + 0]);
    const int e1 = __builtin_amdgcn_readfirstlane(gidx[b * 2 + 1]);
    const float wgt0 = gw[b * 2 + 0];
    const float wgt1 = gw[b * 2 + 1];

    // ---- weight fragments + biases (L2-hot) ----
    bf16x8 a1f[2][2], a2f[2][2];
    #pragma unroll
    for (int ks = 0; ks < 2; ++ks) {
        a1f[0][ks] = *(const bf16x8*)(W1b + e0 * CC * CC + arow * CC + ks * 32 + g * 8);
        a1f[1][ks] = *(const bf16x8*)(W1b + e1 * CC * CC + arow * CC + ks * 32 + g * 8);
        a2f[0][ks] = *(const bf16x8*)(W2b + e0 * CC * CC + arow * CC + ks * 32 + g * 8);
        a2f[1][ks] = *(const bf16x8*)(W2b + e1 * CC * CC + arow * CC + ks * 32 + g * 8);
    }
    const f32x4 b1v0 = *(const f32x4*)(b1 + e0 * CC + r0w);
    const f32x4 b1v1 = *(const f32x4*)(b1 + e1 * CC + r0w);
    const f32x4 b2v0 = *(const f32x4*)(b2 + e0 * CC + r0w);
    const f32x4 b2v1 = *(const f32x4*)(b2 + e1 * CC + r0w);
    const f32x4 kk   = *(const f32x4*)(kvec + b * CC + r0w);
    float bsum[4];
    #pragma unroll
    for (int j = 0; j < 4; ++j) bsum[j] = fmaf(wgt0, b2v0[j], wgt1 * b2v1[j]);

    // ---- load this thread's 16 x values (residual + staging source) ----
    const float* xb = x + b * CC * HWPX;
    const int obase = r0w * HWPX + P0 + l15;
    float xc[16];
    #pragma unroll
    for (int cb = 0; cb < 4; ++cb)
        #pragma unroll
        for (int j = 0; j < 4; ++j)
            xc[cb * 4 + j] = xb[obase + j * HWPX + cb * 16];

    // ---- stage to LDS (bf16 pairs, swizzled) ----
    #pragma unroll
    for (int cb = 0; cb < 4; ++cb) {
        uint2 pk;
        pk.x = packbf2(xc[cb * 4 + 0], xc[cb * 4 + 1]);
        pk.y = packbf2(xc[cb * 4 + 2], xc[cb * 4 + 3]);
        *(uint2*)&LX[swz(cb * 16 + l15, d0)] = pk;
    }
    __syncthreads();   // bar A: xT visible

    // ---- x B-fragments + GEMM1 both experts ----
    f32x4 h0[4], h1[4];
    #pragma unroll
    for (int cb = 0; cb < 4; ++cb) {
        bf16x8 bx0 = *(const bf16x8*)&LX[swz(cb * 16 + l15, g * 4)];
        bf16x8 bx1 = *(const bf16x8*)&LX[swz(cb * 16 + l15, 16 + g * 4)];
        h0[cb] = (f32x4){0.f, 0.f, 0.f, 0.f};
        h1[cb] = (f32x4){0.f, 0.f, 0.f, 0.f};
        h0[cb] = __builtin_amdgcn_mfma_f32_16x16x32_bf16(a1f[0][0], bx0, h0[cb], 0, 0, 0);
        h0[cb] = __builtin_amdgcn_mfma_f32_16x16x32_bf16(a1f[0][1], bx1, h0[cb], 0, 0, 0);
        h1[cb] = __builtin_amdgcn_mfma_f32_16x16x32_bf16(a1f[1][0], bx0, h1[cb], 0, 0, 0);
        h1[cb] = __builtin_amdgcn_mfma_f32_16x16x32_bf16(a1f[1][1], bx1, h1[cb], 0, 0, 0);
    }

    // gelu sigmoid-form: gelu(t) = t * rcp(1 + exp2(t*(C1 + C2*t^2)))
    const float C1 = -2.302208239f;    // -2*log2(e)*0.7978845608
    const float C2 = -0.1029434f;      // C1 * 0.044715

    // ---- gelu + pack both experts (gate weights folded in), write hT0/hT1 ----
    #pragma unroll
    for (int cb = 0; cb < 4; ++cb) {
        float hv0[4], hv1[4];
        #pragma unroll
        for (int j = 0; j < 4; ++j) {
            float t0 = (h0[cb][j] + b1v0[j]) * kk[j];
            float ex0 = __builtin_amdgcn_exp2f(t0 * fmaf(C2, t0 * t0, C1));
            hv0[j] = (t0 * wgt0) * __builtin_amdgcn_rcpf(ex0 + 1.f);
            float t1 = (h1[cb][j] + b1v1[j]) * kk[j];
            float ex1 = __builtin_amdgcn_exp2f(t1 * fmaf(C2, t1 * t1, C1));
            hv1[j] = (t1 * wgt1) * __builtin_amdgcn_rcpf(ex1 + 1.f);
        }
        uint2 pk0, pk1;
        pk0.x = packbf2(hv0[0], hv0[1]);
        pk0.y = packbf2(hv0[2], hv0[3]);
        pk1.x = packbf2(hv1[0], hv1[1]);
        pk1.y = packbf2(hv1[2], hv1[3]);
        *(uint2*)&LH0[swz(cb * 16 + l15, d0)] = pk0;
        *(uint2*)&LH1[swz(cb * 16 + l15, d0)] = pk1;
    }
    __syncthreads();   // bar B: hT0 + hT1 visible

    // ---- GEMM2 both experts ----
    f32x4 acc[4];
    #pragma unroll
    for (int cb = 0; cb < 4; ++cb) {
        acc[cb] = (f32x4){0.f, 0.f, 0.f, 0.f};
        #pragma unroll
        for (int ks = 0; ks < 2; ++ks) {
            bf16x8 bh0 = *(const bf16x8*)&LH0[swz(cb * 16 + l15, ks * 16 + g * 4)];
            acc[cb] = __builtin_amdgcn_mfma_f32_16x16x32_bf16(a2f[0][ks], bh0, acc[cb], 0, 0, 0);
            bf16x8 bh1 = *(const bf16x8*)&LH1[swz(cb * 16 + l15, ks * 16 + g * 4)];
            acc[cb] = __builtin_amdgcn_mfma_f32_16x16x32_bf16(a2f[1][ks], bh1, acc[cb], 0, 0, 0);
        }
    }

    // ---- epilogue: out = x(f32 regs) + acc + gated b2 ----
    float* ob = out + b * CC * HWPX;
    #pragma unroll
    for (int cb = 0; cb < 4; ++cb)
        #pragma unroll
        for (int j = 0; j < 4; ++j)
            ob[obase + j * HWPX + cb * 16] = xc[cb * 4 + j] + (acc[cb][j] + bsum[j]);
}

extern "C" void kernel_launch(void* const* d_in, const int* in_sizes, int n_in,
                              void* d_out, int out_size, void* d_ws, size_t ws_size,
                              hipStream_t stream) {
    const float* x  = (const float*)d_in[0];
    const float* k  = (const float*)d_in[1];
    const float* Wg = (const float*)d_in[2];
    const float* bg = (const float*)d_in[3];
    const float* W1 = (const float*)d_in[4];
    const float* b1 = (const float*)d_in[5];
    const float* W2 = (const float*)d_in[6];
    const float* b2 = (const float*)d_in[7];
    float* out = (float*)d_out;

    // workspace layout
    float*  pooled = (float*)d_ws;                          // 4 KiB
    int*    gidx   = (int*)((char*)d_ws + 4096);            // 128 B
    float*  gw     = (float*)((char*)d_ws + 4096 + 128);    // 128 B
    __bf16* W1b    = (__bf16*)((char*)d_ws + 8192);         // 64 KiB
    __bf16* W2b    = (__bf16*)((char*)d_ws + 8192 + 65536); // 64 KiB

    pool_conv_kernel<<<BB * CC + EE * CC * CC / 256, 256, 0, stream>>>(x, pooled, W1, W2, W1b, W2b);
    gate_kernel<<<1, 64, 0, stream>>>(pooled, Wg, bg, gidx, gw);
    moe_main<<<BB * 256, 256, 0, stream>>>(x, k, W1b, b1, W2b, b2, gidx, gw, out);
}